// Round 9
// baseline (629.147 us; speedup 1.0000x reference)
//
#include <hip/hip_runtime.h>
#include <stdint.h>
#include <stddef.h>

// Problem constants
#define S_LEN 128
#define B_SZ  64
#define V_SZ  32000
#define EH    512
#define EO    512
#define H_SZ  1024
#define O_SZ  1024
#define G3    3072   // 3*H

typedef __attribute__((ext_vector_type(8))) short short8;
typedef __attribute__((ext_vector_type(4))) float floatx4;
typedef __attribute__((ext_vector_type(8))) unsigned short ushortx8;
typedef __attribute__((ext_vector_type(4))) unsigned uintx4;
typedef __attribute__((ext_vector_type(2))) unsigned long long ulonglongx2;

__device__ __forceinline__ unsigned short f2bf(float f) {
  unsigned u = __builtin_bit_cast(unsigned, f);
  u += 0x7FFFu + ((u >> 16) & 1u);   // round-to-nearest-even
  return (unsigned short)(u >> 16);
}
__device__ __forceinline__ float bf2f(unsigned short h) {
  unsigned u = ((unsigned)h) << 16;
  return __builtin_bit_cast(float, u);
}

__device__ __forceinline__ void gld_lds16(const void* g, void* l) {
  __builtin_amdgcn_global_load_lds((const __attribute__((address_space(1))) void*)g,
                                   (__attribute__((address_space(3))) void*)l, 16, 0, 0);
}
// agent-scope stores: visible at the coherence point once vmcnt-acked
// (same discipline as the proven h-exchange)
__device__ __forceinline__ void st8_agent(void* p, unsigned long long v) {
  __hip_atomic_store((unsigned long long*)p, v, __ATOMIC_RELAXED, __HIP_MEMORY_SCOPE_AGENT);
}
__device__ __forceinline__ void st4_agent(void* p, unsigned v) {
  __hip_atomic_store((unsigned*)p, v, __ATOMIC_RELAXED, __HIP_MEMORY_SCOPE_AGENT);
}

// ------------------------------------------------- fused weight prep (ONE launch)
// seg A (256 blocks) : W2 fp32 -> flat bf16; block 0 also zeroes bar (1 KiB)
// seg B (1536 blocks): W_hh -> Wprep, MFMA-B-fragment order (96 chunks / cg)
// seg C (768 blocks) : W_ih -> Wihp, fragment order (48 chunks / cg)
// seg D (512 blocks) : W_out -> Woutp, fragment order (32 chunks / cg)
__global__ __launch_bounds__(256) void prep_all(const float* __restrict__ W2,
                                                const float* __restrict__ W_hh,
                                                const float* __restrict__ W_ih,
                                                const float* __restrict__ W_out,
                                                unsigned short* __restrict__ W2b,
                                                unsigned short* __restrict__ Wprep,
                                                unsigned short* __restrict__ Wihp,
                                                unsigned short* __restrict__ Woutp,
                                                unsigned* __restrict__ bar) {
  int b = blockIdx.x;
  int t = threadIdx.x;
  if (b < 256) {
    int i = b * 256 + t;                       // 65536 float4
    float4 v = ((const float4*)W2)[i];
    ushort4 o;
    o.x = f2bf(v.x); o.y = f2bf(v.y); o.z = f2bf(v.z); o.w = f2bf(v.w);
    ((ushort4*)W2b)[i] = o;
    if (b == 0) bar[t] = 0;                    // 256 dwords = 1 KiB
    return;
  }
  int lane, row, k;
  const float* src;
  ushortx8* dst;
  if (b < 256 + 1536) {
    int tid = (b - 256) * 256 + t;             // 393216
    lane = tid & 63;
    int c = tid >> 6;                          // 0..6143
    int cg = c / 96, r = c % 96, g = r >> 5, tt = r & 31;
    row = g * H_SZ + cg * 16 + (lane & 15);
    k   = tt * 32 + (lane >> 4) * 8;
    src = &W_hh[(size_t)row * H_SZ + k];
    dst = (ushortx8*)Wprep + tid;
  } else if (b < 256 + 1536 + 768) {
    int tid = (b - 1792) * 256 + t;            // 196608
    lane = tid & 63;
    int c = tid >> 6;                          // 0..3071
    int cg = c / 48, r = c % 48, g = r >> 4, kq = r & 15;
    row = g * H_SZ + cg * 16 + (lane & 15);
    k   = kq * 32 + (lane >> 4) * 8;
    src = &W_ih[(size_t)row * EO + k];
    dst = (ushortx8*)Wihp + tid;
  } else {
    int tid = (b - 2560) * 256 + t;            // 131072
    lane = tid & 63;
    int c = tid >> 6;                          // 0..2047
    int cg = c >> 5, kq = c & 31;
    row = cg * 16 + (lane & 15);
    k   = kq * 32 + (lane >> 4) * 8;
    src = &W_out[(size_t)row * H_SZ + k];
    dst = (ushortx8*)Woutp + tid;
  }
  float4 v0 = *(const float4*)src;
  float4 v1 = *(const float4*)(src + 4);
  ushortx8 o;
  o[0] = f2bf(v0.x); o[1] = f2bf(v0.y); o[2] = f2bf(v0.z); o[3] = f2bf(v0.w);
  o[4] = f2bf(v1.x); o[5] = f2bf(v1.y); o[6] = f2bf(v1.z); o[7] = f2bf(v1.w);
  *dst = o;
}

// ------------------------------------------------- fused main kernel
// Cooperative, 256 blocks x 256 threads. Phases (grid-synced via a single
// fetch_add counter at bar[32], targets 256*k -- same proven mechanism as the
// per-bg step barrier):
//   T: W1 [EH][V] fp32 -> W1T bf16 [V][EH]  (agent 8B stores)
//   G: emb = thresh(gather(W1T, ids) + b1)  (sc1 reads, agent 8B stores)
//   X: x = thresh(emb @ W2^T + b2)          (A: sc1 reg-staged; B: W2b via
//      global_load_lds -- coherent across the prep_all kernel boundary;
//      out: lane-paired packed agent dword stores)
//   GRU loop + out epilogue: byte-identical to round 8, except the xf
//      prefetch loads are sc1 (x is produced in-kernel now).
// Coherence rule everywhere: in-kernel cross-block data is WRITTEN with
// agent-scope atomics and READ with sc1 loads; __syncthreads before each
// arrive drains vmcnt so stores are at the LLC (h-exchange discipline).
__global__ __launch_bounds__(256, 1) void gru_persist(const int* __restrict__ ids,
                                                      const float* __restrict__ W1,
                                                      const float* __restrict__ b1,
                                                      const unsigned short* __restrict__ W2b,
                                                      const float* __restrict__ b2,
                                                      unsigned short* __restrict__ W1T,
                                                      unsigned short* __restrict__ emb,
                                                      unsigned short* __restrict__ x,
                                                      const unsigned short* __restrict__ hprep0,
                                                      unsigned short* __restrict__ hprep1,
                                                      unsigned short* __restrict__ hbfinal,
                                                      const unsigned short* __restrict__ Wprep,
                                                      const unsigned short* __restrict__ Wihp,
                                                      const unsigned short* __restrict__ Woutp,
                                                      const float* __restrict__ b_hh,
                                                      const float* __restrict__ b_ih,
                                                      const float* __restrict__ b_out,
                                                      float* __restrict__ out,
                                                      unsigned* __restrict__ bar) {
  __shared__ unsigned short lB[96 * 512];    // 98304 B : phases T/X scratch; W_hh; W_out
  __shared__ unsigned short lWih[48 * 512];  // 49152 B : W_ih slice, fragment order
  __shared__ float lgh[3][4][256];           // 12288 B : per-wave K-partials (r,z merged)
  __shared__ float lgxn[4][256];             //  4096 B : per-wave xW n-gate partials
  // total 163840 B = full 160 KiB LDS
  int t = threadIdx.x;
  int lane = t & 63;
  int w = t >> 6;
  int bid = blockIdx.x;
  int bg = bid >> 6;    // 0..3
  int cg = bid & 63;    // 0..63

  unsigned* gctr = bar + 32;    // grid-sync counter (per-bg step counters at 0/64/128/192)
  auto grid_sync = [&](unsigned target) {
    __syncthreads();            // drains vmcnt: this block's agent stores are at LLC
    if (t == 0) {
      __hip_atomic_fetch_add(gctr, 1u, __ATOMIC_RELAXED, __HIP_MEMORY_SCOPE_AGENT);
      while (__hip_atomic_load(gctr, __ATOMIC_RELAXED, __HIP_MEMORY_SCOPE_AGENT) < target)
        __builtin_amdgcn_s_sleep(2);
    }
    __syncthreads();
  };

  // ---------------- phase T: W1 transpose -> W1T bf16 ----------------
  {
    unsigned short (*tile)[72] = (unsigned short (*)[72])lB;   // 9216 B
    for (int tile_id = bid; tile_id < 4000; tile_id += 256) {
      int v0 = (tile_id % 500) * 64;
      int e0 = (tile_id / 500) * 64;
      __syncthreads();   // protect tile from previous iteration's readers
      for (int i = 0; i < 4; ++i) {
        int e = (t >> 4) + i * 16;
        int v = (t & 15) * 4;
        float4 wv = *(const float4*)&W1[(size_t)(e0 + e) * V_SZ + v0 + v];
        tile[v + 0][e] = f2bf(wv.x);
        tile[v + 1][e] = f2bf(wv.y);
        tile[v + 2][e] = f2bf(wv.z);
        tile[v + 3][e] = f2bf(wv.w);
      }
      __syncthreads();
      for (int i = 0; i < 2; ++i) {
        int v = (t >> 3) + i * 32;
        int e = (t & 7) * 8;
        ushortx8 o;
        for (int j = 0; j < 8; ++j) o[j] = tile[v][e + j];
        ulonglongx2 p = __builtin_bit_cast(ulonglongx2, o);
        unsigned long long* dst = (unsigned long long*)&W1T[(size_t)(v0 + v) * EH + e0 + e];
        st8_agent(dst, p[0]);
        st8_agent(dst + 1, p[1]);
      }
    }
  }
  grid_sync(256);

  // ---------------- phase G: emb = thresh(W1T[ids] + b1) ----------------
  {
    float4 blo = *(const float4*)&b1[lane * 8];
    float4 bhi = *(const float4*)&b1[lane * 8 + 4];
    float bv[8] = {blo.x, blo.y, blo.z, blo.w, bhi.x, bhi.y, bhi.z, bhi.w};
    int tok0 = bid * 4 + w;
    uintx4 wv[8];
#pragma unroll
    for (int it = 0; it < 8; ++it) {
      int id = ids[tok0 + it * 1024];
      const void* ap = &W1T[(size_t)id * EH + lane * 8];
      asm volatile("global_load_dwordx4 %0, %1, off sc1" : "=v"(wv[it]) : "v"(ap));
    }
    asm volatile("s_waitcnt vmcnt(0)"
                 : "+v"(wv[0]), "+v"(wv[1]), "+v"(wv[2]), "+v"(wv[3]),
                   "+v"(wv[4]), "+v"(wv[5]), "+v"(wv[6]), "+v"(wv[7])
                 :: "memory");
#pragma unroll
    for (int it = 0; it < 8; ++it) {
      ushortx8 w8 = __builtin_bit_cast(ushortx8, wv[it]);
      ushortx8 o;
#pragma unroll
      for (int j = 0; j < 8; ++j) {
        float xv = bf2f(w8[j]) + bv[j];
        xv = (xv > 1e-6f) ? xv : 0.0f;
        o[j] = f2bf(xv);
      }
      ulonglongx2 p = __builtin_bit_cast(ulonglongx2, o);
      unsigned long long* dst =
          (unsigned long long*)&emb[(size_t)(tok0 + it * 1024) * EH + lane * 8];
      st8_agent(dst, p[0]);
      st8_agent(dst + 1, p[1]);
    }
  }
  grid_sync(512);

  // ---------------- phase X: x = thresh(emb @ W2^T + b2) ----------------
  // grid maps 1:1: bn = bid>>6 (N/128=4), bm = bid&63 (M/128=64).
  {
    unsigned short* xlA = lB;              // 16 KB
    unsigned short* xlB = lB + 128 * 64;   // 16 KB
    int bn = bid >> 6;
    int bm = bid & 63;
    int wm = (w >> 1) * 64;
    int wn = (w & 1) * 64;
    floatx4 acc[4][4] = {};
    int srow = t >> 3;
    int sslot = (t & 7) ^ (srow & 7);      // T2 swizzle on the global source slot
    int scol = sslot * 8;
    const unsigned short* aptr[4];
    const unsigned short* bptr[4];
#pragma unroll
    for (int p = 0; p < 4; ++p) {
      aptr[p] = emb + (size_t)(bm * 128 + p * 32 + srow) * EH + scol;
      bptr[p] = W2b + (size_t)(bn * 128 + p * 32 + srow) * EH + scol;
    }
    for (int k0 = 0; k0 < EH; k0 += 64) {
      __syncthreads();
      uintx4 sa[4];
#pragma unroll
      for (int p = 0; p < 4; ++p) {
        asm volatile("global_load_dwordx4 %0, %1, off sc1" : "=v"(sa[p]) : "v"(aptr[p] + k0));
        gld_lds16(bptr[p] + k0, &xlB[p * 2048 + t * 8]);
      }
      asm volatile("s_waitcnt vmcnt(0)"
                   : "+v"(sa[0]), "+v"(sa[1]), "+v"(sa[2]), "+v"(sa[3]) :: "memory");
#pragma unroll
      for (int p = 0; p < 4; ++p)
        *(uintx4*)&xlA[p * 2048 + t * 8] = sa[p];
      __syncthreads();
#pragma unroll
      for (int kk = 0; kk < 2; ++kk) {
        short8 af[4], bfr[4];
#pragma unroll
        for (int i = 0; i < 4; ++i) {
          int row = wm + i * 16 + (lane & 15);
          int phys = (kk * 4 + (lane >> 4)) ^ (row & 7);
          af[i] = *(const short8*)&xlA[row * 64 + phys * 8];
        }
#pragma unroll
        for (int j = 0; j < 4; ++j) {
          int row = wn + j * 16 + (lane & 15);
          int phys = (kk * 4 + (lane >> 4)) ^ (row & 7);
          bfr[j] = *(const short8*)&xlB[row * 64 + phys * 8];
        }
#pragma unroll
        for (int i = 0; i < 4; ++i)
#pragma unroll
          for (int j = 0; j < 4; ++j)
            acc[i][j] = __builtin_amdgcn_mfma_f32_16x16x32_bf16(af[i], bfr[j], acc[i][j], 0, 0, 0);
      }
    }
    // epilogue: packed agent dword stores (lane pairs share a row, adjacent cols)
    int rowq = (lane >> 4) * 4;
    for (int j = 0; j < 4; ++j) {
      int col = bn * 128 + wn + j * 16 + (lane & 15);
      float bv = b2[col];
      for (int i = 0; i < 4; ++i) {
        int row0 = bm * 128 + wm + i * 16 + rowq;
        for (int r = 0; r < 4; ++r) {
          int row = row0 + r;
          float v = acc[i][j][r] + bv;
          v = (v > 1e-6f) ? v : 0.0f;
          unsigned hb = (unsigned)f2bf(v);
          unsigned other = (unsigned)__shfl_xor((int)hb, 1);
          if ((lane & 1) == 0)
            st4_agent((unsigned*)x + (((size_t)row * EO + col) >> 1), hb | (other << 16));
        }
      }
    }
  }
  grid_sync(768);

  // ---------------- GRU (byte-identical to round 8; xf loads sc1) ----------------
  // stage W_hh slice once (identity copy, 98 KB; Wprep from prep_all dispatch)
  const unsigned short* wsrc = Wprep + (size_t)cg * 96 * 512;
  for (int i = 0; i < 24; ++i) {
    int c = w * 24 + i;
    gld_lds16(wsrc + (size_t)c * 512 + lane * 8, &lB[c * 512 + lane * 8]);
  }
  // stage W_ih slice once (48 KB)
  const unsigned short* wxs = Wihp + (size_t)cg * 48 * 512;
  for (int i = 0; i < 12; ++i) {
    int c = w * 12 + i;
    gld_lds16(wxs + (size_t)c * 512 + lane * 8, &lWih[c * 512 + lane * 8]);
  }

  int b_loc = t >> 4;
  int j_loc = t & 15;
  int jcol = cg * 16 + j_loc;          // h column
  int bglob = bg * 16 + b_loc;         // batch
  float brz_r = b_hh[jcol] + b_ih[jcol];                    // merged r bias
  float brz_z = b_hh[H_SZ + jcol] + b_ih[H_SZ + jcol];      // merged z bias
  float bhn  = b_hh[2 * H_SZ + jcol];
  float bihn = b_ih[2 * H_SZ + jcol];
  int tt2 = jcol >> 5;
  int q   = (jcol >> 3) & 3;
  int jj  = jcol & 7;
  int Ls  = b_loc | (q << 4);
  size_t hw_off32 = ((((size_t)(bg * 32 + tt2) * 64 + Ls) * 8) + (jj & ~1)) >> 1;

  const unsigned short* hbufs[2] = {hprep0, hprep1};
  unsigned* barp = bar + bg * 64;      // per-bg counter, 256 B apart
  float hmaster = 0.0f;

  const unsigned short* xbase =
      x + ((size_t)(bg * 16 + (lane & 15))) * EO + (lane >> 4) * 8 + (w * 4) * 32;

  __syncthreads();   // drains staging vmcnt (lB + lWih ready)

  // prologue: xf prefetch for s=0 (sc1: x was written in-kernel)
  uintx4 xf[4];
#pragma unroll
  for (int i = 0; i < 4; ++i)
    asm volatile("global_load_dwordx4 %0, %1, off sc1" : "=v"(xf[i]) : "v"(xbase + i * 32));

  for (int s = 0; s < S_LEN; ++s) {
    const unsigned short* hr = hbufs[s & 1];
    unsigned* hw32 = (unsigned*)hbufs[(s + 1) & 1];

    uintx4 av[8];
    if (s == 0) {
#pragma unroll
      for (int i = 0; i < 8; ++i) av[i] = (uintx4){0u, 0u, 0u, 0u};
    } else {
#pragma unroll
      for (int i = 0; i < 8; ++i) {
        int tt = w * 8 + i;
        const void* ap = hr + ((size_t)(bg * 32 + tt) * 64 + lane) * 8;
        asm volatile("global_load_dwordx4 %0, %1, off sc1" : "=v"(av[i]) : "v"(ap));
      }
    }
    asm volatile("s_waitcnt vmcnt(0)"
                 : "+v"(av[0]), "+v"(av[1]), "+v"(av[2]), "+v"(av[3]),
                   "+v"(av[4]), "+v"(av[5]), "+v"(av[6]), "+v"(av[7]),
                   "+v"(xf[0]), "+v"(xf[1]), "+v"(xf[2]), "+v"(xf[3])
                 :: "memory");

    floatx4 acc[3] = {};
    floatx4 accn = {};
#pragma unroll
    for (int i = 0; i < 8; ++i) {
      int tt = w * 8 + i;
      short8 a = __builtin_bit_cast(short8, av[i]);
#pragma unroll
      for (int g = 0; g < 3; ++g) {
        short8 bfr = *(const short8*)&lB[((g * 32 + tt) * 64 + lane) * 8];
        acc[g] = __builtin_amdgcn_mfma_f32_16x16x32_bf16(a, bfr, acc[g], 0, 0, 0);
      }
    }
#pragma unroll
    for (int i = 0; i < 4; ++i) {
      int kq = w * 4 + i;
      short8 a = __builtin_bit_cast(short8, xf[i]);
      short8 b0 = *(const short8*)&lWih[((0 * 16 + kq) * 64 + lane) * 8];
      short8 b1f = *(const short8*)&lWih[((1 * 16 + kq) * 64 + lane) * 8];
      short8 b2f = *(const short8*)&lWih[((2 * 16 + kq) * 64 + lane) * 8];
      acc[0] = __builtin_amdgcn_mfma_f32_16x16x32_bf16(a, b0, acc[0], 0, 0, 0);
      acc[1] = __builtin_amdgcn_mfma_f32_16x16x32_bf16(a, b1f, acc[1], 0, 0, 0);
      accn   = __builtin_amdgcn_mfma_f32_16x16x32_bf16(a, b2f, accn,   0, 0, 0);
    }

    if (s + 1 < S_LEN) {
      const unsigned short* xrow = xbase + (size_t)(s + 1) * B_SZ * EO;
#pragma unroll
      for (int i = 0; i < 4; ++i)
        asm volatile("global_load_dwordx4 %0, %1, off sc1" : "=v"(xf[i]) : "v"(xrow + i * 32));
    }

#pragma unroll
    for (int g = 0; g < 3; ++g)
#pragma unroll
      for (int r = 0; r < 4; ++r)
        lgh[g][w][((lane >> 4) * 4 + r) * 16 + (lane & 15)] = acc[g][r];
#pragma unroll
    for (int r = 0; r < 4; ++r)
      lgxn[w][((lane >> 4) * 4 + r) * 16 + (lane & 15)] = accn[r];
    __syncthreads();

    float grs = lgh[0][0][t] + lgh[0][1][t] + lgh[0][2][t] + lgh[0][3][t] + brz_r;
    float gzs = lgh[1][0][t] + lgh[1][1][t] + lgh[1][2][t] + lgh[1][3][t] + brz_z;
    float ghn = lgh[2][0][t] + lgh[2][1][t] + lgh[2][2][t] + lgh[2][3][t] + bhn;
    float xnv = lgxn[0][t] + lgxn[1][t] + lgxn[2][t] + lgxn[3][t] + bihn;
    float rr = 1.0f / (1.0f + __expf(-grs));
    float zz = 1.0f / (1.0f + __expf(-gzs));
    float nn = tanhf(xnv + rr * ghn);
    float hnew = (1.0f - zz) * nn + zz * hmaster;
    hmaster = hnew;

    unsigned hb = (unsigned)f2bf(hnew);
    unsigned other = (unsigned)__shfl_xor((int)hb, 1);
    if ((jj & 1) == 0) {
      unsigned packed = hb | (other << 16);   // (jj, jj+1)
      st4_agent(hw32 + hw_off32, packed);
      if (s == S_LEN - 1)
        st4_agent((unsigned*)hbfinal + (((size_t)bglob * H_SZ + jcol) >> 1), packed);
    }

    // per-bg barrier EVERY step (incl. last: publishes hbfinal for epilogue)
    __syncthreads();   // waitcnt vmcnt(0) + barrier: h-stores at L3, xf loaded
    if (t == 0) {
      __hip_atomic_fetch_add(barp, 1u, __ATOMIC_RELAXED, __HIP_MEMORY_SCOPE_AGENT);
      unsigned target = 64u * (unsigned)(s + 1);
      while (__hip_atomic_load(barp, __ATOMIC_RELAXED, __HIP_MEMORY_SCOPE_AGENT) < target)
        __builtin_amdgcn_s_sleep(2);
    }
    __syncthreads();   // release
  }

  // ---- epilogue: out = h @ W_out^T + b_out ----
  {
    const unsigned short* wos = Woutp + (size_t)cg * 32 * 512;
#pragma unroll
    for (int i = 0; i < 8; ++i) {
      int c = w * 8 + i;
      gld_lds16(wos + (size_t)c * 512 + lane * 8, &lB[c * 512 + lane * 8]);
    }
    uintx4 hv[8];
#pragma unroll
    for (int i = 0; i < 8; ++i) {
      int kq = w * 8 + i;
      const void* hp = hbfinal + (size_t)(bg * 16 + (lane & 15)) * H_SZ +
                       kq * 32 + (lane >> 4) * 8;
      asm volatile("global_load_dwordx4 %0, %1, off sc1" : "=v"(hv[i]) : "v"(hp));
    }
    __syncthreads();   // drains staging + register loads
    asm volatile("s_waitcnt vmcnt(0)"
                 : "+v"(hv[0]), "+v"(hv[1]), "+v"(hv[2]), "+v"(hv[3]),
                   "+v"(hv[4]), "+v"(hv[5]), "+v"(hv[6]), "+v"(hv[7])
                 :: "memory");
    floatx4 acco = {};
#pragma unroll
    for (int i = 0; i < 8; ++i) {
      int kq = w * 8 + i;
      short8 a = __builtin_bit_cast(short8, hv[i]);
      short8 bfr = *(const short8*)&lB[kq * 512 + lane * 8];
      acco = __builtin_amdgcn_mfma_f32_16x16x32_bf16(a, bfr, acco, 0, 0, 0);
    }
#pragma unroll
    for (int r = 0; r < 4; ++r)
      lgh[0][w][((lane >> 4) * 4 + r) * 16 + (lane & 15)] = acco[r];
    __syncthreads();
    float o = lgh[0][0][t] + lgh[0][1][t] + lgh[0][2][t] + lgh[0][3][t] + b_out[jcol];
    out[(size_t)bglob * O_SZ + jcol] = o;
  }
}

// ----------------------------------------------------------------- launch
extern "C" void kernel_launch(void* const* d_in, const int* in_sizes, int n_in,
                              void* d_out, int out_size, void* d_ws, size_t ws_size,
                              hipStream_t stream) {
  const int*   ids   = (const int*)d_in[0];
  const float* W1    = (const float*)d_in[1];
  const float* b1    = (const float*)d_in[2];
  const float* W2    = (const float*)d_in[3];
  const float* b2    = (const float*)d_in[4];
  const float* W_ih  = (const float*)d_in[5];
  const float* b_ih  = (const float*)d_in[6];
  const float* W_hh  = (const float*)d_in[7];
  const float* b_hh  = (const float*)d_in[8];
  const float* W_out = (const float*)d_in[9];
  const float* b_out = (const float*)d_in[10];
  float* out = (float*)d_out;

  uint8_t* wsp = (uint8_t*)d_ws;
  auto alloc = [&](size_t bytes) {
    uint8_t* p = wsp;
    wsp += (bytes + 255) & ~(size_t)255;
    return p;
  };
  unsigned short* W1T   = (unsigned short*)alloc((size_t)V_SZ * EH * 2);
  unsigned short* W2b   = (unsigned short*)alloc((size_t)EO * EH * 2);
  unsigned short* Wprep = (unsigned short*)alloc((size_t)G3 * H_SZ * 2);
  unsigned short* Wihp  = (unsigned short*)alloc((size_t)G3 * EO * 2);
  unsigned short* Woutp = (unsigned short*)alloc((size_t)O_SZ * H_SZ * 2);
  unsigned short* emb   = (unsigned short*)alloc((size_t)S_LEN * B_SZ * EH * 2);
  unsigned short* x     = (unsigned short*)alloc((size_t)S_LEN * B_SZ * EO * 2);
  unsigned short* hprep0 = (unsigned short*)alloc((size_t)B_SZ * H_SZ * 2);
  unsigned short* hprep1 = (unsigned short*)alloc((size_t)B_SZ * H_SZ * 2);
  unsigned short* hbfinal = (unsigned short*)alloc((size_t)B_SZ * H_SZ * 2);
  unsigned*       bar     = (unsigned*)alloc(1024);

  // weight prep (W2 cvt, W_hh/W_ih/W_out fragment prep, bar zeroing)
  prep_all<<<dim3(3072), 256, 0, stream>>>(W2, W_hh, W_ih, W_out,
                                           W2b, Wprep, Wihp, Woutp, bar);

  // everything else: ONE cooperative kernel (transpose, gather, x-GEMM as
  // grid-synced pre-phases; then the GRU loop + out epilogue).
  {
    void* args[] = {(void*)&ids, (void*)&W1, (void*)&b1, (void*)&W2b, (void*)&b2,
                    (void*)&W1T, (void*)&emb, (void*)&x,
                    (void*)&hprep0, (void*)&hprep1, (void*)&hbfinal,
                    (void*)&Wprep, (void*)&Wihp, (void*)&Woutp,
                    (void*)&b_hh, (void*)&b_ih, (void*)&b_out,
                    (void*)&out, (void*)&bar};
    hipLaunchCooperativeKernel((const void*)gru_persist, dim3(256), dim3(256),
                               args, 0, stream);
  }
}

// Round 10
// 572.737 us; speedup vs baseline: 1.0985x; 1.0985x over previous
//
#include <hip/hip_runtime.h>
#include <stdint.h>
#include <stddef.h>

// Problem constants
#define S_LEN 128
#define B_SZ  64
#define V_SZ  32000
#define EH    512
#define EO    512
#define H_SZ  1024
#define O_SZ  1024
#define G3    3072   // 3*H

typedef __attribute__((ext_vector_type(8))) short short8;
typedef __attribute__((ext_vector_type(4))) float floatx4;
typedef __attribute__((ext_vector_type(8))) unsigned short ushortx8;
typedef __attribute__((ext_vector_type(4))) unsigned uintx4;

__device__ __forceinline__ unsigned short f2bf(float f) {
  unsigned u = __builtin_bit_cast(unsigned, f);
  u += 0x7FFFu + ((u >> 16) & 1u);   // round-to-nearest-even
  return (unsigned short)(u >> 16);
}
__device__ __forceinline__ float bf2f(unsigned short h) {
  unsigned u = ((unsigned)h) << 16;
  return __builtin_bit_cast(float, u);
}

__device__ __forceinline__ void gld_lds16(const void* g, void* l) {
  __builtin_amdgcn_global_load_lds((const __attribute__((address_space(1))) void*)g,
                                   (__attribute__((address_space(3))) void*)l, 16, 0, 0);
}

// ------------------------------------------------- fused transpose + weight prep
// (ONE high-occupancy launch; round-9 lesson: bulk memory-bound phases must NOT
// live inside the 160-KB-LDS cooperative kernel -- they need many blocks/CU.)
// blocks [0,4000)     : W1 [EH][V] -> W1T bf16 [V][EH], one 64x64 tile each
// blocks [4000,+256)  : W2 fp32 -> flat bf16; first block zeroes bar (1 KiB)
// blocks [+256,+1536) : W_hh -> Wprep, MFMA-B-fragment order (96 chunks / cg)
// blocks [+1536,+768) : W_ih -> Wihp, fragment order (48 chunks / cg)
// blocks [+768,+512)  : W_out -> Woutp, fragment order (32 chunks / cg)
__global__ __launch_bounds__(256) void prep_transpose(const float* __restrict__ W1,
                                                      const float* __restrict__ W2,
                                                      const float* __restrict__ W_hh,
                                                      const float* __restrict__ W_ih,
                                                      const float* __restrict__ W_out,
                                                      unsigned short* __restrict__ W1T,
                                                      unsigned short* __restrict__ W2b,
                                                      unsigned short* __restrict__ Wprep,
                                                      unsigned short* __restrict__ Wihp,
                                                      unsigned short* __restrict__ Woutp,
                                                      unsigned* __restrict__ bar) {
  __shared__ unsigned short tile[64][72];   // transpose scratch, padded
  int b = blockIdx.x;
  int t = threadIdx.x;
  if (b < 4000) {
    int v0 = (b % 500) * 64;
    int e0 = (b / 500) * 64;
    for (int i = 0; i < 4; ++i) {
      int e = (t >> 4) + i * 16;
      int v = (t & 15) * 4;
      float4 w = *(const float4*)&W1[(size_t)(e0 + e) * V_SZ + v0 + v];
      tile[v + 0][e] = f2bf(w.x);
      tile[v + 1][e] = f2bf(w.y);
      tile[v + 2][e] = f2bf(w.z);
      tile[v + 3][e] = f2bf(w.w);
    }
    __syncthreads();
    for (int i = 0; i < 2; ++i) {
      int v = (t >> 3) + i * 32;
      int e = (t & 7) * 8;
      ushortx8 o;
      for (int j = 0; j < 8; ++j) o[j] = tile[v][e + j];
      *(ushortx8*)&W1T[(size_t)(v0 + v) * EH + e0 + e] = o;
    }
    return;
  }
  b -= 4000;
  if (b < 256) {
    int i = b * 256 + t;                       // 65536 float4
    float4 v = ((const float4*)W2)[i];
    ushort4 o;
    o.x = f2bf(v.x); o.y = f2bf(v.y); o.z = f2bf(v.z); o.w = f2bf(v.w);
    ((ushort4*)W2b)[i] = o;
    if (b == 0) bar[t] = 0;                    // 256 dwords = 1 KiB
    return;
  }
  int lane, row, k;
  const float* src;
  ushortx8* dst;
  if (b < 256 + 1536) {
    int tid = (b - 256) * 256 + t;             // 393216
    lane = tid & 63;
    int c = tid >> 6;                          // 0..6143
    int cg = c / 96, r = c % 96, g = r >> 5, tt = r & 31;
    row = g * H_SZ + cg * 16 + (lane & 15);
    k   = tt * 32 + (lane >> 4) * 8;
    src = &W_hh[(size_t)row * H_SZ + k];
    dst = (ushortx8*)Wprep + tid;
  } else if (b < 256 + 1536 + 768) {
    int tid = (b - 1792) * 256 + t;            // 196608
    lane = tid & 63;
    int c = tid >> 6;                          // 0..3071
    int cg = c / 48, r = c % 48, g = r >> 4, kq = r & 15;
    row = g * H_SZ + cg * 16 + (lane & 15);
    k   = kq * 32 + (lane >> 4) * 8;
    src = &W_ih[(size_t)row * EO + k];
    dst = (ushortx8*)Wihp + tid;
  } else {
    int tid = (b - 2560) * 256 + t;            // 131072
    lane = tid & 63;
    int c = tid >> 6;                          // 0..2047
    int cg = c >> 5, kq = c & 31;
    row = cg * 16 + (lane & 15);
    k   = kq * 32 + (lane >> 4) * 8;
    src = &W_out[(size_t)row * H_SZ + k];
    dst = (ushortx8*)Woutp + tid;
  }
  float4 v0 = *(const float4*)src;
  float4 v1 = *(const float4*)(src + 4);
  ushortx8 o;
  o[0] = f2bf(v0.x); o[1] = f2bf(v0.y); o[2] = f2bf(v0.z); o[3] = f2bf(v0.w);
  o[4] = f2bf(v1.x); o[5] = f2bf(v1.y); o[6] = f2bf(v1.z); o[7] = f2bf(v1.w);
  *dst = o;
}

// ------------------------------------------------- x = thresh(thresh(W1T[ids]+b1) @ W2^T + b2)
// gemm_bt specialization with the GATHER FOLDED INTO A-STAGING: A rows are
// W1T[ids[row]] with +b1 and threshold applied in registers during staging
// (emb is never materialized: saves one dispatch + 16 MB of traffic).
// B-side keeps the BK=64 + T2 XOR-swizzle global_load_lds path; A writes the
// same swizzled 16-B slots via ds_write_b128 after the register transform.
__global__ __launch_bounds__(256) void gemm_x(const int* __restrict__ ids,
                                              const unsigned short* __restrict__ W1T,
                                              const float* __restrict__ b1,
                                              const unsigned short* __restrict__ W2b,
                                              const float* __restrict__ b2,
                                              unsigned short* __restrict__ x) {
  __shared__ unsigned short lA[128 * 64];   // 16 KB, [row][slot^(row&7)] 16-B slots
  __shared__ unsigned short lB[128 * 64];   // 16 KB
  int t = threadIdx.x;
  int lane = t & 63;
  int wave = t >> 6;
  int bn = blockIdx.x, bm = blockIdx.y;
  int wm = (wave >> 1) * 64;
  int wn = (wave & 1) * 64;
  floatx4 acc[4][4] = {};

  int srow = t >> 3;                       // 0..31 within pass
  int sslot = (t & 7) ^ (srow & 7);        // logical (global) 16-B slot
  int scol = sslot * 8;                    // element offset within BK=64

  // per-thread token ids for the 4 A-staging passes (fixed across K)
  int aid[4];
  const unsigned short* bptr[4];
#pragma unroll
  for (int p = 0; p < 4; ++p) {
    aid[p] = ids[bm * 128 + p * 32 + srow];
    bptr[p] = W2b + (size_t)(bn * 128 + p * 32 + srow) * EH + scol;
  }

  for (int k0 = 0; k0 < EH; k0 += 64) {
    __syncthreads();
    // B staging (async to LDS), A gather-loads to registers
    uintx4 va[4];
#pragma unroll
    for (int p = 0; p < 4; ++p) {
      gld_lds16(bptr[p] + k0, &lB[p * 2048 + t * 8]);
      va[p] = *(const uintx4*)&W1T[(size_t)aid[p] * EH + k0 + scol];
    }
    float4 b1lo = *(const float4*)&b1[k0 + scol];
    float4 b1hi = *(const float4*)&b1[k0 + scol + 4];
    float bv[8] = {b1lo.x, b1lo.y, b1lo.z, b1lo.w, b1hi.x, b1hi.y, b1hi.z, b1hi.w};
#pragma unroll
    for (int p = 0; p < 4; ++p) {
      ushortx8 w8 = __builtin_bit_cast(ushortx8, va[p]);
      ushortx8 o;
#pragma unroll
      for (int j = 0; j < 8; ++j) {
        float v = bf2f(w8[j]) + bv[j];
        v = (v > 1e-6f) ? v : 0.0f;       // emb threshold
        o[j] = f2bf(v);
      }
      *(ushortx8*)&lA[p * 2048 + t * 8] = o;
    }
    __syncthreads();
#pragma unroll
    for (int kk = 0; kk < 2; ++kk) {
      short8 af[4], bfr[4];
#pragma unroll
      for (int i = 0; i < 4; ++i) {
        int row = wm + i * 16 + (lane & 15);
        int phys = (kk * 4 + (lane >> 4)) ^ (row & 7);
        af[i] = *(const short8*)&lA[row * 64 + phys * 8];
      }
#pragma unroll
      for (int j = 0; j < 4; ++j) {
        int row = wn + j * 16 + (lane & 15);
        int phys = (kk * 4 + (lane >> 4)) ^ (row & 7);
        bfr[j] = *(const short8*)&lB[row * 64 + phys * 8];
      }
#pragma unroll
      for (int i = 0; i < 4; ++i)
#pragma unroll
        for (int j = 0; j < 4; ++j)
          acc[i][j] = __builtin_amdgcn_mfma_f32_16x16x32_bf16(af[i], bfr[j], acc[i][j], 0, 0, 0);
    }
  }

  int rowq = (lane >> 4) * 4;
  for (int j = 0; j < 4; ++j) {
    int col = bn * 128 + wn + j * 16 + (lane & 15);
    float bv = b2[col];
    for (int i = 0; i < 4; ++i) {
      int row0 = bm * 128 + wm + i * 16 + rowq;
      for (int r = 0; r < 4; ++r) {
        int row = row0 + r;
        float v = acc[i][j][r] + bv;
        v = (v > 1e-6f) ? v : 0.0f;
        x[(size_t)row * EO + col] = f2bf(v);
      }
    }
  }
}

// ------------------------------------------------- persistent GRU recurrence
// EXACT round-8 kernel (measured 398.5 us): 256 blocks x 256 threads,
// cooperative. Block (bg,cg): batches [bg*16,+16), h-cols [cg*16,+16);
// wave w = K-quarter. Frozen round-0 barrier (4 variants regressed).
// xW fold in the main MFMA block (xf prefetched one full step ahead);
// s==0 zero-h shortcut; out-GEMM folded into the epilogue.
__global__ __launch_bounds__(256, 1) void gru_persist(const unsigned short* __restrict__ hprep0,
                                                      unsigned short* __restrict__ hprep1,
                                                      unsigned short* __restrict__ hbfinal,
                                                      const unsigned short* __restrict__ Wprep,
                                                      const unsigned short* __restrict__ Wihp,
                                                      const unsigned short* __restrict__ Woutp,
                                                      const float* __restrict__ b_hh,
                                                      const float* __restrict__ b_ih,
                                                      const float* __restrict__ b_out,
                                                      const unsigned short* __restrict__ x,
                                                      float* __restrict__ out,
                                                      unsigned* __restrict__ bar) {
  __shared__ unsigned short lB[96 * 512];    // 98304 B : W_hh slice; W_out slice in epilogue
  __shared__ unsigned short lWih[48 * 512];  // 49152 B : W_ih slice, fragment order
  __shared__ float lgh[3][4][256];           // 12288 B : per-wave K-partials (r,z merged)
  __shared__ float lgxn[4][256];             //  4096 B : per-wave xW n-gate partials
  // total 163840 B = full 160 KiB LDS
  int t = threadIdx.x;
  int lane = t & 63;
  int w = t >> 6;
  int bg = blockIdx.x >> 6;    // 0..3
  int cg = blockIdx.x & 63;    // 0..63

  // stage W_hh slice once (identity copy, 98 KB)
  const unsigned short* wsrc = Wprep + (size_t)cg * 96 * 512;
  for (int i = 0; i < 24; ++i) {
    int c = w * 24 + i;
    gld_lds16(wsrc + (size_t)c * 512 + lane * 8, &lB[c * 512 + lane * 8]);
  }
  // stage W_ih slice once (48 KB)
  const unsigned short* wxs = Wihp + (size_t)cg * 48 * 512;
  for (int i = 0; i < 12; ++i) {
    int c = w * 12 + i;
    gld_lds16(wxs + (size_t)c * 512 + lane * 8, &lWih[c * 512 + lane * 8]);
  }

  // per-thread update-element constants
  int b_loc = t >> 4;
  int j_loc = t & 15;
  int jcol = cg * 16 + j_loc;          // h column
  int bglob = bg * 16 + b_loc;         // batch
  float brz_r = b_hh[jcol] + b_ih[jcol];                    // merged r bias
  float brz_z = b_hh[H_SZ + jcol] + b_ih[H_SZ + jcol];      // merged z bias
  float bhn  = b_hh[2 * H_SZ + jcol];
  float bihn = b_ih[2 * H_SZ + jcol];
  // scatter-store position for h_new (A-fragment layout); lane pairs (jj even/odd)
  // pack 2 bf16 into one dword store.
  int tt2 = jcol >> 5;
  int q   = (jcol >> 3) & 3;
  int jj  = jcol & 7;
  int Ls  = b_loc | (q << 4);
  size_t hw_off32 = ((((size_t)(bg * 32 + tt2) * 64 + Ls) * 8) + (jj & ~1)) >> 1;

  const unsigned short* hbufs[2] = {hprep0, hprep1};
  unsigned* barp = bar + bg * 64;      // per-bg counter, 256 B apart
  float hmaster = 0.0f;                // fp32 master h for my (batch, col)

  // per-lane base for xW A-fragments (batch = lane&15, k0 = (lane>>4)*8);
  // wave w owns kq = 4w..4w+3  -> element offset kq*32
  const unsigned short* xbase =
      x + ((size_t)(bg * 16 + (lane & 15))) * EO + (lane >> 4) * 8 + (w * 4) * 32;

  __syncthreads();   // drains staging vmcnt (lB + lWih ready)

  // prologue: issue xf prefetch for s=0 (the loop's tied vmcnt(0) waits them)
  uintx4 xf[4];
#pragma unroll
  for (int i = 0; i < 4; ++i)
    asm volatile("global_load_dwordx4 %0, %1, off" : "=v"(xf[i]) : "v"(xbase + i * 32));

  for (int s = 0; s < S_LEN; ++s) {
    const unsigned short* hr = hbufs[s & 1];
    unsigned* hw32 = (unsigned*)hbufs[(s + 1) & 1];

    // A-fragments for my K-quarter. s==0: h0 == 0 -> zero fragments, no loads.
    uintx4 av[8];
    if (s == 0) {
#pragma unroll
      for (int i = 0; i < 8; ++i) av[i] = (uintx4){0u, 0u, 0u, 0u};
    } else {
#pragma unroll
      for (int i = 0; i < 8; ++i) {
        int tt = w * 8 + i;
        const void* ap = hr + ((size_t)(bg * 32 + tt) * 64 + lane) * 8;
        asm volatile("global_load_dwordx4 %0, %1, off sc1" : "=v"(av[i]) : "v"(ap));
      }
    }
    asm volatile("s_waitcnt vmcnt(0)"
                 : "+v"(av[0]), "+v"(av[1]), "+v"(av[2]), "+v"(av[3]),
                   "+v"(av[4]), "+v"(av[5]), "+v"(av[6]), "+v"(av[7]),
                   "+v"(xf[0]), "+v"(xf[1]), "+v"(xf[2]), "+v"(xf[3])
                 :: "memory");

    // main MFMA block: 24 W_hh MFMAs + 12 xW MFMAs (r,z merged into acc[0/1])
    floatx4 acc[3] = {};
    floatx4 accn = {};
#pragma unroll
    for (int i = 0; i < 8; ++i) {
      int tt = w * 8 + i;
      short8 a = __builtin_bit_cast(short8, av[i]);
#pragma unroll
      for (int g = 0; g < 3; ++g) {
        short8 bfr = *(const short8*)&lB[((g * 32 + tt) * 64 + lane) * 8];
        acc[g] = __builtin_amdgcn_mfma_f32_16x16x32_bf16(a, bfr, acc[g], 0, 0, 0);
      }
    }
#pragma unroll
    for (int i = 0; i < 4; ++i) {
      int kq = w * 4 + i;
      short8 a = __builtin_bit_cast(short8, xf[i]);
      short8 b0 = *(const short8*)&lWih[((0 * 16 + kq) * 64 + lane) * 8];
      short8 b1f = *(const short8*)&lWih[((1 * 16 + kq) * 64 + lane) * 8];
      short8 b2f = *(const short8*)&lWih[((2 * 16 + kq) * 64 + lane) * 8];
      acc[0] = __builtin_amdgcn_mfma_f32_16x16x32_bf16(a, b0, acc[0], 0, 0, 0);
      acc[1] = __builtin_amdgcn_mfma_f32_16x16x32_bf16(a, b1f, acc[1], 0, 0, 0);
      accn   = __builtin_amdgcn_mfma_f32_16x16x32_bf16(a, b2f, accn,   0, 0, 0);
    }

    // prefetch x A-fragments for step s+1 (full-step cover, 4 loads/thread)
    if (s + 1 < S_LEN) {
      const unsigned short* xrow = xbase + (size_t)(s + 1) * B_SZ * EO;
#pragma unroll
      for (int i = 0; i < 4; ++i)
        asm volatile("global_load_dwordx4 %0, %1, off" : "=v"(xf[i]) : "v"(xrow + i * 32));
    }

#pragma unroll
    for (int g = 0; g < 3; ++g)
#pragma unroll
      for (int r = 0; r < 4; ++r)
        lgh[g][w][((lane >> 4) * 4 + r) * 16 + (lane & 15)] = acc[g][r];
#pragma unroll
    for (int r = 0; r < 4; ++r)
      lgxn[w][((lane >> 4) * 4 + r) * 16 + (lane & 15)] = accn[r];
    __syncthreads();

    // gate update for my element (sum 4 K-partials; r,z already merged)
    float grs = lgh[0][0][t] + lgh[0][1][t] + lgh[0][2][t] + lgh[0][3][t] + brz_r;
    float gzs = lgh[1][0][t] + lgh[1][1][t] + lgh[1][2][t] + lgh[1][3][t] + brz_z;
    float ghn = lgh[2][0][t] + lgh[2][1][t] + lgh[2][2][t] + lgh[2][3][t] + bhn;
    float xnv = lgxn[0][t] + lgxn[1][t] + lgxn[2][t] + lgxn[3][t] + bihn;
    float rr = 1.0f / (1.0f + __expf(-grs));
    float zz = 1.0f / (1.0f + __expf(-gzs));
    float nn = tanhf(xnv + rr * ghn);
    float hnew = (1.0f - zz) * nn + zz * hmaster;
    hmaster = hnew;

    unsigned hb = (unsigned)f2bf(hnew);
    unsigned other = (unsigned)__shfl_xor((int)hb, 1);
    if ((jj & 1) == 0) {
      unsigned packed = hb | (other << 16);   // (jj, jj+1)
      __hip_atomic_store(hw32 + hw_off32, packed,
                         __ATOMIC_RELAXED, __HIP_MEMORY_SCOPE_AGENT);
      if (s == S_LEN - 1) {
        __hip_atomic_store((unsigned*)hbfinal + (((size_t)bglob * H_SZ + jcol) >> 1),
                           packed, __ATOMIC_RELAXED, __HIP_MEMORY_SCOPE_AGENT);
      }
    }

    // per-bg barrier EVERY step (incl. last: publishes hbfinal for epilogue)
    __syncthreads();   // waitcnt vmcnt(0) + barrier: h-stores at L3, xf loaded
    if (t == 0) {
      __hip_atomic_fetch_add(barp, 1u, __ATOMIC_RELAXED, __HIP_MEMORY_SCOPE_AGENT);
      unsigned target = 64u * (unsigned)(s + 1);
      while (__hip_atomic_load(barp, __ATOMIC_RELAXED, __HIP_MEMORY_SCOPE_AGENT) < target)
        __builtin_amdgcn_s_sleep(2);
    }
    __syncthreads();   // release
  }

  // ---- epilogue: out = h @ W_out^T + b_out (folded final GEMM) ----
  {
    const unsigned short* wos = Woutp + (size_t)cg * 32 * 512;
#pragma unroll
    for (int i = 0; i < 8; ++i) {
      int c = w * 8 + i;
      gld_lds16(wos + (size_t)c * 512 + lane * 8, &lB[c * 512 + lane * 8]);
    }
    uintx4 hv[8];
#pragma unroll
    for (int i = 0; i < 8; ++i) {
      int kq = w * 8 + i;
      const void* hp = hbfinal + (size_t)(bg * 16 + (lane & 15)) * H_SZ +
                       kq * 32 + (lane >> 4) * 8;
      asm volatile("global_load_dwordx4 %0, %1, off sc1" : "=v"(hv[i]) : "v"(hp));
    }
    __syncthreads();   // drains staging + register loads
    asm volatile("s_waitcnt vmcnt(0)"
                 : "+v"(hv[0]), "+v"(hv[1]), "+v"(hv[2]), "+v"(hv[3]),
                   "+v"(hv[4]), "+v"(hv[5]), "+v"(hv[6]), "+v"(hv[7])
                 :: "memory");
    floatx4 acco = {};
#pragma unroll
    for (int i = 0; i < 8; ++i) {
      int kq = w * 8 + i;
      short8 a = __builtin_bit_cast(short8, hv[i]);
      short8 bfr = *(const short8*)&lB[kq * 512 + lane * 8];
      acco = __builtin_amdgcn_mfma_f32_16x16x32_bf16(a, bfr, acco, 0, 0, 0);
    }
#pragma unroll
    for (int r = 0; r < 4; ++r)
      lgh[0][w][((lane >> 4) * 4 + r) * 16 + (lane & 15)] = acco[r];
    __syncthreads();
    float o = lgh[0][0][t] + lgh[0][1][t] + lgh[0][2][t] + lgh[0][3][t] + b_out[jcol];
    out[(size_t)bglob * O_SZ + jcol] = o;
  }
}

// ----------------------------------------------------------------- launch
extern "C" void kernel_launch(void* const* d_in, const int* in_sizes, int n_in,
                              void* d_out, int out_size, void* d_ws, size_t ws_size,
                              hipStream_t stream) {
  const int*   ids   = (const int*)d_in[0];
  const float* W1    = (const float*)d_in[1];
  const float* b1    = (const float*)d_in[2];
  const float* W2    = (const float*)d_in[3];
  const float* b2    = (const float*)d_in[4];
  const float* W_ih  = (const float*)d_in[5];
  const float* b_ih  = (const float*)d_in[6];
  const float* W_hh  = (const float*)d_in[7];
  const float* b_hh  = (const float*)d_in[8];
  const float* W_out = (const float*)d_in[9];
  const float* b_out = (const float*)d_in[10];
  float* out = (float*)d_out;

  uint8_t* wsp = (uint8_t*)d_ws;
  auto alloc = [&](size_t bytes) {
    uint8_t* p = wsp;
    wsp += (bytes + 255) & ~(size_t)255;
    return p;
  };
  unsigned short* W1T   = (unsigned short*)alloc((size_t)V_SZ * EH * 2);
  unsigned short* W2b   = (unsigned short*)alloc((size_t)EO * EH * 2);
  unsigned short* Wprep = (unsigned short*)alloc((size_t)G3 * H_SZ * 2);
  unsigned short* Wihp  = (unsigned short*)alloc((size_t)G3 * EO * 2);
  unsigned short* Woutp = (unsigned short*)alloc((size_t)O_SZ * H_SZ * 2);
  unsigned short* x     = (unsigned short*)alloc((size_t)S_LEN * B_SZ * EO * 2);
  unsigned short* hprep0 = (unsigned short*)alloc((size_t)B_SZ * H_SZ * 2);
  unsigned short* hprep1 = (unsigned short*)alloc((size_t)B_SZ * H_SZ * 2);
  unsigned short* hbfinal = (unsigned short*)alloc((size_t)B_SZ * H_SZ * 2);
  unsigned*       bar     = (unsigned*)alloc(1024);

  // W1 transpose + ALL weight prep in one high-occupancy launch
  prep_transpose<<<dim3(4000 + 3072), 256, 0, stream>>>(
      W1, W2, W_hh, W_ih, W_out, W1T, W2b, Wprep, Wihp, Woutp, bar);

  // x = thresh(thresh(W1T[ids]+b1) @ W2^T + b2)  -- gather folded into A-staging
  gemm_x<<<dim3(EO / 128, S_LEN * B_SZ / 128), 256, 0, stream>>>(
      ids, W1T, b1, W2b, b2, x);

  // persistent GRU recurrence (cooperative: all 256 blocks co-resident)
  {
    void* args[] = {(void*)&hprep0, (void*)&hprep1, (void*)&hbfinal,
                    (void*)&Wprep, (void*)&Wihp, (void*)&Woutp,
                    (void*)&b_hh, (void*)&b_ih, (void*)&b_out,
                    (void*)&x, (void*)&out, (void*)&bar};
    hipLaunchCooperativeKernel((const void*)gru_persist, dim3(256), dim3(256),
                               args, 0, stream);
  }
}